// Round 6
// baseline (175.255 us; speedup 1.0000x reference)
//
#include <hip/hip_runtime.h>
#include <stdint.h>

#define NFFT    1024
#define HOP     160
#define NMELS   160
#define SEG     32000
#define PADW    512
#define XLEN    33024            // SEG + 2*PADW
#define NFRAMES 201
#define NBATCH  256
#define NFREQ   256              // bins 0..255 cover all nonzero mel weights
#define TOTFR   (NBATCH * NFRAMES)   // 51456 = 402 * 128
#define FBW     12
#define BM      128
#define BN      128              // real bins per block (2 block-columns)
#define BK      32
#define NSTEP   (NFFT / BK)      // 32

using bf16x8 = __attribute__((ext_vector_type(8))) __bf16;
using f32x4  = __attribute__((ext_vector_type(4))) float;

static __device__ __forceinline__ uint16_t f2bf(float f) {
    union { float f; uint32_t u; } v; v.f = f;
    return (uint16_t)((v.u + 0x7FFFu + ((v.u >> 16) & 1u)) >> 16);
}

static __device__ __forceinline__ void gload16(const void* g, void* l) {
    __builtin_amdgcn_global_load_lds(
        (const __attribute__((address_space(1))) uint32_t*)(uintptr_t)g,
        (__attribute__((address_space(3))) uint32_t*)(uintptr_t)l,
        16, 0, 0);
}

// ---- prep 1: reflect-pad waveform -> bf16, 8 elems/thread
__global__ void k_pad(const float* __restrict__ wav, uint16_t* __restrict__ wp) {
    int i0 = (blockIdx.x * 256 + threadIdx.x) * 8;
    int b  = blockIdx.y;
    if (i0 >= XLEN) return;
    uint16_t r[8];
    if (i0 >= PADW && i0 + 8 <= PADW + SEG) {
        const float* s = wav + (size_t)b * SEG + (i0 - PADW);
        float4 v0 = *(const float4*)s;
        float4 v1 = *(const float4*)(s + 4);
        r[0]=f2bf(v0.x); r[1]=f2bf(v0.y); r[2]=f2bf(v0.z); r[3]=f2bf(v0.w);
        r[4]=f2bf(v1.x); r[5]=f2bf(v1.y); r[6]=f2bf(v1.z); r[7]=f2bf(v1.w);
    } else {
        #pragma unroll
        for (int e = 0; e < 8; ++e) {
            int i = i0 + e;
            int j = i - PADW;
            j = (j < 0) ? -j : ((j >= SEG) ? (2 * SEG - 2 - j) : j);
            r[e] = f2bf(wav[(size_t)b * SEG + j]);
        }
    }
    *(uint4*)(wp + (size_t)b * XLEN + i0) = *(const uint4*)r;
}

// ---- prep 2: BT[mat][n][k] = bf16(dft[mat][n][k] * window[k]), 8 elems/thread
__global__ void k_bt(const float* __restrict__ dre, const float* __restrict__ dimg,
                     const float* __restrict__ win, uint16_t* __restrict__ BT) {
    int idx8 = blockIdx.x * 256 + threadIdx.x;       // 65536 threads
    int mat = idx8 >> 15;
    int n   = (idx8 >> 7) & 255;
    int k0  = (idx8 & 127) * 8;
    const float* src = (mat ? dimg : dre) + (size_t)n * 1024 + k0;
    const float* w   = win + k0;
    float4 s0 = *(const float4*)src,       s1 = *(const float4*)(src + 4);
    float4 w0 = *(const float4*)w,         w1 = *(const float4*)(w + 4);
    uint16_t r[8];
    r[0]=f2bf(s0.x*w0.x); r[1]=f2bf(s0.y*w0.y); r[2]=f2bf(s0.z*w0.z); r[3]=f2bf(s0.w*w0.w);
    r[4]=f2bf(s1.x*w1.x); r[5]=f2bf(s1.y*w1.y); r[6]=f2bf(s1.z*w1.z); r[7]=f2bf(s1.w*w1.w);
    *(uint4*)(BT + (size_t)idx8 * 8) = *(const uint4*)r;
}

// ---- prep 3: compact sparse mel filterbank rows
__global__ void k_fb(const float* __restrict__ fb, int* __restrict__ klo,
                     int* __restrict__ kw, float* __restrict__ fbv) {
    int m = threadIdx.x;
    if (m >= NMELS) return;
    int lo = -1, hi = -1;
    for (int f = 0; f < NFREQ; ++f) {
        float v = fb[m * 513 + f];
        if (v > 0.f) { if (lo < 0) lo = f; hi = f; }
    }
    int w = (lo < 0) ? 0 : (hi - lo + 1);
    if (w > FBW) w = FBW;
    if (lo < 0) lo = 0;
    klo[m] = lo; kw[m] = w;
    for (int j = 0; j < w; ++j) fbv[m * FBW + j] = fb[m * 513 + lo + j];
}

// ---- prep 4: zero outputs that get atomicAdd'ed (straddle/empty mel rows)
__global__ void k_zero(const int* __restrict__ klo, const int* __restrict__ kw,
                       float* __restrict__ out) {
    int b = blockIdx.x;
    for (int m = 0; m < NMELS; ++m) {
        int lo = klo[m], w = kw[m];
        bool straddle = (lo < BN && lo + w > BN);
        if (!(straddle || w == 0)) continue;
        for (int t = threadIdx.x; t < NFRAMES; t += blockDim.x)
            out[(size_t)b * NMELS * NFRAMES + m * NFRAMES + t] = 0.f;
    }
}

// ---- main GEMM: 128 frames x 128 bins (R+I), K=1024.
// A: DIRECT global->VGPR (one 16B frag/lane = one 64B line per frame per K-step,
//    L1/L2-resident, software-pipelined one K-step ahead).
// B: LDS triple-buffered 3x16KB @ 0/16K/32K, R5 chunk swizzle (c ^= (row>>1)&3).
// vmcnt ledger (issue order S,A per iter): steady entry [S(t+1):2][A(t):4];
//   +S(t+2)+A(t+1)=12 -> vmcnt(6) drains S(t+1)+A(t). t=30: vmcnt(4); t=31: 0.
// Epilogue: power as f32 in LDS overlay [128][128], col ^ (row&31) swizzle.
__global__ __launch_bounds__(512, 4) void k_main(
    const uint16_t* __restrict__ wp, const uint16_t* __restrict__ BT,
    const int* __restrict__ klo, const int* __restrict__ kw,
    const float* __restrict__ fbv, float* __restrict__ out)
{
    __shared__ uint4 smem4[65536 / 16];          // 64 KB -> 2 blocks/CU
    char* smem = (char*)smem4;

    const int tid  = threadIdx.x;
    const int lane = tid & 63;
    const int wave = tid >> 6;                   // 8 waves: 2(M) x 4(N)
    const int wm = wave >> 2, wn = wave & 3;
    const int l15 = lane & 15, lg = lane >> 4;
    const int gBase = blockIdx.x * BM;
    const int nb    = blockIdx.y;                // bin half: 0 or 1

    // ---- B staging: 16 slots of 1KB (16 rows x 64B), 2 per wave
    const int lrow = lane >> 2;
    const int lchk = lane & 3;
    const int schunk = lchk ^ ((lrow >> 1) & 3);
    const uint16_t* bsrc[2];
    uint32_t brel[2];
    #pragma unroll
    for (int i = 0; i < 2; ++i) {
        int s  = wave * 2 + i;                   // 0..15
        int vr = s * 16 + lrow;                  // 0..255 (Re 0-127, Im 128-255)
        int mat = vr >> 7, bin = vr & 127;
        bsrc[i] = BT + (size_t)(mat * 256 + nb * BN + bin) * 1024 + schunk * 8;
        brel[i] = (uint32_t)s * 1024 + lane * 16;
    }

    // ---- A fragment base pointers (per mi): frame row, 16B at lg*8
    const uint16_t* aptr[4];
    #pragma unroll
    for (int mi = 0; mi < 4; ++mi) {
        int g = gBase + wm * 64 + mi * 16 + l15;
        int b = g / NFRAMES, t = g - b * NFRAMES;
        aptr[mi] = wp + (size_t)b * XLEN + t * HOP + lg * 8;
    }

    auto STAGE = [&](int buf, int ks) {
        #pragma unroll
        for (int i = 0; i < 2; ++i)
            gload16(bsrc[i] + (size_t)ks * BK,
                    smem + (uint32_t)buf * 16384u + brel[i]);
    };
    auto LOADA = [&](bf16x8 (&dst)[4], int ks) {
        #pragma unroll
        for (int mi = 0; mi < 4; ++mi)
            dst[mi] = *(const bf16x8*)(aptr[mi] + ks * BK);
    };

    f32x4 accR[4][2], accI[4][2];
    #pragma unroll
    for (int mi = 0; mi < 4; ++mi)
        #pragma unroll
        for (int ni = 0; ni < 2; ++ni) {
            accR[mi][ni] = f32x4{0.f, 0.f, 0.f, 0.f};
            accI[mi][ni] = f32x4{0.f, 0.f, 0.f, 0.f};
        }

    bf16x8 aR0[4], aR1[4];
    const int rchunk = (lg ^ ((l15 >> 1) & 3)) * 16;

    auto MFMA_BLOCK = [&](bf16x8 (&a)[4], const char* Bc) {
        bf16x8 br[2], bi[2];
        #pragma unroll
        for (int ni = 0; ni < 2; ++ni) {
            br[ni] = *(const bf16x8*)(Bc + (wn * 32 + ni * 16 + l15) * 64 + rchunk);
            bi[ni] = *(const bf16x8*)(Bc + 8192 + (wn * 32 + ni * 16 + l15) * 64 + rchunk);
        }
        return (void)0, br[0], bi[0], br[1], bi[1];  // (unused; real reads below)
    };
    (void)MFMA_BLOCK;

    // prologue: S(0), A(0), S(1)  -> ages [S0:2][A0:4][S1:2]
    STAGE(0, 0);
    LOADA(aR0, 0);
    STAGE(1, 1);
    asm volatile("s_waitcnt vmcnt(6)" ::: "memory");   // drain S0
    __builtin_amdgcn_s_barrier();
    __builtin_amdgcn_sched_barrier(0);

    #pragma unroll
    for (int t = 0; t < NSTEP; ++t) {
        if (t + 2 < NSTEP) STAGE((t + 2) % 3, t + 2);
        if (t + 1 < NSTEP) {
            if ((t & 1) == 0) LOADA(aR1, t + 1);
            else              LOADA(aR0, t + 1);
        }
        const char* Bc = smem + (uint32_t)(t % 3) * 16384u;
        bf16x8 br[2], bi[2];
        #pragma unroll
        for (int ni = 0; ni < 2; ++ni) {
            br[ni] = *(const bf16x8*)(Bc + (wn * 32 + ni * 16 + l15) * 64 + rchunk);
            bi[ni] = *(const bf16x8*)(Bc + 8192 + (wn * 32 + ni * 16 + l15) * 64 + rchunk);
        }
        if (t + 3 <= NSTEP)      // t <= 29
            asm volatile("s_waitcnt vmcnt(6) lgkmcnt(0)" ::: "memory");
        else if (t == NSTEP - 2)
            asm volatile("s_waitcnt vmcnt(4) lgkmcnt(0)" ::: "memory");
        else
            asm volatile("s_waitcnt vmcnt(0) lgkmcnt(0)" ::: "memory");
        __builtin_amdgcn_sched_barrier(0);

        __builtin_amdgcn_s_setprio(1);
        if ((t & 1) == 0) {
            #pragma unroll
            for (int mi = 0; mi < 4; ++mi)
                #pragma unroll
                for (int ni = 0; ni < 2; ++ni) {
                    accR[mi][ni] = __builtin_amdgcn_mfma_f32_16x16x32_bf16(
                        aR0[mi], br[ni], accR[mi][ni], 0, 0, 0);
                    accI[mi][ni] = __builtin_amdgcn_mfma_f32_16x16x32_bf16(
                        aR0[mi], bi[ni], accI[mi][ni], 0, 0, 0);
                }
        } else {
            #pragma unroll
            for (int mi = 0; mi < 4; ++mi)
                #pragma unroll
                for (int ni = 0; ni < 2; ++ni) {
                    accR[mi][ni] = __builtin_amdgcn_mfma_f32_16x16x32_bf16(
                        aR1[mi], br[ni], accR[mi][ni], 0, 0, 0);
                    accI[mi][ni] = __builtin_amdgcn_mfma_f32_16x16x32_bf16(
                        aR1[mi], bi[ni], accI[mi][ni], 0, 0, 0);
                }
        }
        __builtin_amdgcn_s_setprio(0);
        __builtin_amdgcn_sched_barrier(0);
        __builtin_amdgcn_s_barrier();
    }

    // ---- epilogue: power f32 -> LDS overlay [128][128], col ^ (row&31)
    float* pw = (float*)smem;
    #pragma unroll
    for (int mi = 0; mi < 4; ++mi)
        #pragma unroll
        for (int ni = 0; ni < 2; ++ni)
            #pragma unroll
            for (int e = 0; e < 4; ++e) {
                int row = wm * 64 + mi * 16 + lg * 4 + e;
                int col = wn * 32 + ni * 16 + l15;
                float r = accR[mi][ni][e], im = accI[mi][ni][e];
                pw[row * BN + (col ^ (row & 31))] = r * r + im * im;
            }
    __syncthreads();

    // ---- sparse mel projection + transposed store/atomic out[b][m][t]
    const int nbase = nb * BN;
    const int ti = tid & 127;                    // fixed per thread
    {
        int g = gBase + ti;
        int b = g / NFRAMES, tt = g - b * NFRAMES;
        const int sw = ti & 31;
        const float* prow = pw + ti * BN;
        float* obase = out + (size_t)b * (NMELS * NFRAMES) + tt;
        for (int m = (tid >> 7); m < NMELS; m += 4) {
            int lo = klo[m], w = kw[m];
            int i0 = lo < nbase ? nbase : lo;
            int i1 = (lo + w < nbase + BN) ? (lo + w) : (nbase + BN);
            if (i1 <= i0) continue;
            float acc = 0.f;
            for (int j = i0; j < i1; ++j)
                acc += fbv[m * FBW + (j - lo)] * prow[(j - nbase) ^ sw];
            float* dst = obase + m * NFRAMES;
            bool full = (lo >= nbase) && (lo + w <= nbase + BN);
            if (full) *dst = acc;
            else      atomicAdd(dst, acc);
        }
    }
}

extern "C" void kernel_launch(void* const* d_in, const int* in_sizes, int n_in,
                              void* d_out, int out_size, void* d_ws, size_t ws_size,
                              hipStream_t stream) {
    const float* wav  = (const float*)d_in[0];
    const float* win  = (const float*)d_in[1];
    const float* dre  = (const float*)d_in[2];
    const float* dimg = (const float*)d_in[3];
    const float* mfb  = (const float*)d_in[4];
    float* out = (float*)d_out;

    uint8_t* ws = (uint8_t*)d_ws;
    uint16_t* BT  = (uint16_t*)ws;                       // 1 MB
    uint16_t* wp  = (uint16_t*)(ws + (1u << 20));        // 16.9 MB
    size_t off = (1u << 20) + (size_t)NBATCH * XLEN * 2;
    int*   klo = (int*)(ws + off);
    int*   kw  = (int*)(ws + off + 640);
    float* fbv = (float*)(ws + off + 1280);

    hipLaunchKernelGGL(k_bt,   dim3(256),          dim3(256), 0, stream, dre, dimg, win, BT);
    hipLaunchKernelGGL(k_pad,  dim3(XLEN/8/256 + 1, 256), dim3(256), 0, stream, wav, wp);
    hipLaunchKernelGGL(k_fb,   dim3(1),            dim3(192), 0, stream, mfb, klo, kw, fbv);
    hipLaunchKernelGGL(k_zero, dim3(256),          dim3(256), 0, stream, klo, kw, out);
    hipLaunchKernelGGL(k_main, dim3(TOTFR / BM, 2), dim3(512), 0, stream,
                       wp, BT, klo, kw, fbv, out);
}

// Round 8
// 141.028 us; speedup vs baseline: 1.2427x; 1.2427x over previous
//
#include <hip/hip_runtime.h>
#include <stdint.h>

#define NFFT    1024
#define HOP     160
#define NMELS   160
#define SEG     32000
#define PADW    512
#define XLEN    33024            // SEG + 2*PADW
#define NFRAMES 201
#define NBATCH  256
#define NFREQ   256              // bins 0..255 cover all nonzero mel weights
#define TOTFR   (NBATCH * NFRAMES)   // 51456 = 402 * 128
#define FBW     12
#define BM      128
#define BN      128              // real bins per block (grid.y = 2 halves)
#define BK      32
#define NSTEP   (NFFT / BK)      // 32

using bf16x8 = __attribute__((ext_vector_type(8))) __bf16;
using f32x4  = __attribute__((ext_vector_type(4))) float;

static __device__ __forceinline__ uint16_t f2bf(float f) {
    union { float f; uint32_t u; } v; v.f = f;
    return (uint16_t)((v.u + 0x7FFFu + ((v.u >> 16) & 1u)) >> 16);
}

static __device__ __forceinline__ void gload16(const void* g, void* l) {
    __builtin_amdgcn_global_load_lds(
        (const __attribute__((address_space(1))) uint32_t*)(uintptr_t)g,
        (__attribute__((address_space(3))) uint32_t*)(uintptr_t)l,
        16, 0, 0);
}

// ---- prep 1: reflect-pad waveform -> bf16, 8 elems/thread
__global__ void k_pad(const float* __restrict__ wav, uint16_t* __restrict__ wp) {
    int i0 = (blockIdx.x * 256 + threadIdx.x) * 8;
    int b  = blockIdx.y;
    if (i0 >= XLEN) return;
    uint16_t r[8];
    if (i0 >= PADW && i0 + 8 <= PADW + SEG) {
        const float* s = wav + (size_t)b * SEG + (i0 - PADW);
        float4 v0 = *(const float4*)s;
        float4 v1 = *(const float4*)(s + 4);
        r[0]=f2bf(v0.x); r[1]=f2bf(v0.y); r[2]=f2bf(v0.z); r[3]=f2bf(v0.w);
        r[4]=f2bf(v1.x); r[5]=f2bf(v1.y); r[6]=f2bf(v1.z); r[7]=f2bf(v1.w);
    } else {
        #pragma unroll
        for (int e = 0; e < 8; ++e) {
            int i = i0 + e;
            int j = i - PADW;
            j = (j < 0) ? -j : ((j >= SEG) ? (2 * SEG - 2 - j) : j);
            r[e] = f2bf(wav[(size_t)b * SEG + j]);
        }
    }
    *(uint4*)(wp + (size_t)b * XLEN + i0) = *(const uint4*)r;
}

// ---- prep 2: BTf in FRAGMENT-MAJOR order:
// frag(mat, ntile, kstep) = 1KB: lane l (l15=bin%16, lg=k-chunk) holds 8 bf16
//   element (bin = ntile*16 + l15, k = kstep*32 + lg*8 + j), window folded in.
// flat: (((mat*16 + ntile)*32 + kstep)*64 + lane)*8
__global__ void k_btf(const float* __restrict__ dre, const float* __restrict__ dimg,
                      const float* __restrict__ win, uint16_t* __restrict__ BTf) {
    int idx8 = blockIdx.x * 256 + threadIdx.x;       // 65536 threads
    int lane  = idx8 & 63;
    int kstep = (idx8 >> 6) & 31;
    int ntile = (idx8 >> 11) & 15;
    int mat   = idx8 >> 15;
    int bin = ntile * 16 + (lane & 15);
    int k0  = kstep * 32 + (lane >> 4) * 8;
    const float* src = (mat ? dimg : dre) + (size_t)bin * 1024 + k0;
    const float* w   = win + k0;
    uint16_t r[8];
    #pragma unroll
    for (int j = 0; j < 8; ++j) r[j] = f2bf(src[j] * w[j]);
    *(uint4*)(BTf + (size_t)idx8 * 8) = *(const uint4*)r;
}

// ---- prep 3: compact sparse mel filterbank rows
__global__ void k_fb(const float* __restrict__ fb, int* __restrict__ klo,
                     int* __restrict__ kw, float* __restrict__ fbv) {
    int m = threadIdx.x;
    if (m >= NMELS) return;
    int lo = -1, hi = -1;
    for (int f = 0; f < NFREQ; ++f) {
        float v = fb[m * 513 + f];
        if (v > 0.f) { if (lo < 0) lo = f; hi = f; }
    }
    int w = (lo < 0) ? 0 : (hi - lo + 1);
    if (w > FBW) w = FBW;
    if (lo < 0) lo = 0;
    klo[m] = lo; kw[m] = w;
    for (int j = 0; j < w; ++j) fbv[m * FBW + j] = fb[m * 513 + lo + j];
}

// ---- prep 4: zero outputs that get atomicAdd'ed (straddle/empty mel rows)
__global__ void k_zero(const int* __restrict__ klo, const int* __restrict__ kw,
                       float* __restrict__ out) {
    int b = blockIdx.x;
    for (int m = 0; m < NMELS; ++m) {
        int lo = klo[m], w = kw[m];
        bool straddle = (lo < BN && lo + w > BN);
        if (!(straddle || w == 0)) continue;
        for (int t = threadIdx.x; t < NFRAMES; t += blockDim.x)
            out[(size_t)b * NMELS * NFRAMES + m * NFRAMES + t] = 0.f;
    }
}

// ---- main GEMM: 128 frames x 128 bins (R+I), K=1024.
// A: LDS, triple-buffered 3x8KB, chunk swizzle (conflict-free; 1 gload16/thread/step).
// B: DIRECT global->VGPR from fragment-major BTf (one contiguous 1KB
//    global_load_dwordx4 per wave per frag, 16B/lane, L2-resident).
// Sync invariant: before EVERY s_barrier, each wave drains its own staging for
// the next-read buffer (vmcnt(1) leaves only the newest staging in flight).
// Producer drain BEFORE barrier => cross-wave LDS visibility (R7 bug fix:
// the old order {barrier; vmcnt} raced on iteration 0).
__global__ __launch_bounds__(512, 4) void k_main(
    const uint16_t* __restrict__ wp, const uint16_t* __restrict__ BTf,
    const int* __restrict__ klo, const int* __restrict__ kw,
    const float* __restrict__ fbv, float* __restrict__ out)
{
    __shared__ uint4 smem4[65536 / 16];          // 64 KB (A bufs 24KB; pw overlay)
    char* smem = (char*)smem4;

    const int tid  = threadIdx.x;
    const int lane = tid & 63;
    const int wave = tid >> 6;                   // 8 waves: 2(M) x 4(N)
    const int wm = wave >> 2, wn = wave & 3;
    const int l15 = lane & 15, lg = lane >> 4;
    const int gBase = blockIdx.x * BM;
    const int nb    = blockIdx.y;                // bin half: 0 or 1

    // ---- A staging: 1 chunk per thread. row = tid>>2, chunk = tid&3
    const int arow   = tid >> 2;
    const int schunk = (tid & 3) ^ ((arow >> 1) & 3);   // inverse swizzle
    const uint16_t* asrc;
    {
        int g = gBase + arow;
        int b = g / NFRAMES, t = g - b * NFRAMES;
        asrc = wp + (size_t)b * XLEN + t * HOP + schunk * 8;
    }
    const uint32_t arel = (uint32_t)tid * 16;

    // ---- B fragment-major base: (mat, ntile = nb*8 + wn*2 + ni, kstep=t)
    const uint16_t* bbase = BTf + (size_t)(nb * 8 + wn * 2) * 32 * 512 + lane * 8;
    // offsets (uint16 units): ni -> +16384, mat -> +262144, t -> +512

    auto STAGEA = [&](int buf, int ks) {
        gload16(asrc + (size_t)ks * BK, smem + (uint32_t)buf * 8192u + arel);
    };

    f32x4 accR[4][2], accI[4][2];
    #pragma unroll
    for (int mi = 0; mi < 4; ++mi)
        #pragma unroll
        for (int ni = 0; ni < 2; ++ni) {
            accR[mi][ni] = f32x4{0.f, 0.f, 0.f, 0.f};
            accI[mi][ni] = f32x4{0.f, 0.f, 0.f, 0.f};
        }

    const int rchunk = (lg ^ ((l15 >> 1) & 3)) * 16;

    // prologue: stage buf0, buf1; drain OWN buf0 staging; barrier -> all landed
    STAGEA(0, 0);
    STAGEA(1, 1);
    asm volatile("s_waitcnt vmcnt(1)" ::: "memory");
    __builtin_amdgcn_s_barrier();
    __builtin_amdgcn_sched_barrier(0);

    #pragma unroll
    for (int t = 0; t < NSTEP; ++t) {
        // entry invariant: buf t%3 landed and barrier-visible
        if (t + 2 < NSTEP) STAGEA((t + 2) % 3, t + 2);

        // B frags: contiguous 1KB per wave per frag, from global (L2)
        bf16x8 br[2], bi[2];
        #pragma unroll
        for (int ni = 0; ni < 2; ++ni) {
            br[ni] = *(const bf16x8*)(bbase + ni * 16384 + t * 512);
            bi[ni] = *(const bf16x8*)(bbase + 262144 + ni * 16384 + t * 512);
        }
        // A frags from LDS (compiler inserts lgkmcnt deps)
        const char* Ac = smem + (uint32_t)(t % 3) * 8192u;
        bf16x8 a[4];
        #pragma unroll
        for (int mi = 0; mi < 4; ++mi)
            a[mi] = *(const bf16x8*)(Ac + (wm * 64 + mi * 16 + l15) * 64 + rchunk);

        __builtin_amdgcn_s_setprio(1);
        #pragma unroll
        for (int mi = 0; mi < 4; ++mi)
            #pragma unroll
            for (int ni = 0; ni < 2; ++ni) {
                accR[mi][ni] = __builtin_amdgcn_mfma_f32_16x16x32_bf16(
                    a[mi], br[ni], accR[mi][ni], 0, 0, 0);
                accI[mi][ni] = __builtin_amdgcn_mfma_f32_16x16x32_bf16(
                    a[mi], bi[ni], accI[mi][ni], 0, 0, 0);
            }
        __builtin_amdgcn_s_setprio(0);

        // tail: drain own staging for buf (t+1)%3 (all but newest), then barrier
        if (t + 1 < NSTEP) {
            __builtin_amdgcn_sched_barrier(0);
            asm volatile("s_waitcnt vmcnt(1)" ::: "memory");
            __builtin_amdgcn_s_barrier();
            __builtin_amdgcn_sched_barrier(0);
        }
    }

    __syncthreads();                             // all A-reads done; reuse LDS

    // ---- epilogue: power f32 -> LDS overlay [128][128], col ^ (row&31)
    float* pw = (float*)smem;
    #pragma unroll
    for (int mi = 0; mi < 4; ++mi)
        #pragma unroll
        for (int ni = 0; ni < 2; ++ni)
            #pragma unroll
            for (int e = 0; e < 4; ++e) {
                int row = wm * 64 + mi * 16 + lg * 4 + e;
                int col = wn * 32 + ni * 16 + l15;
                float r = accR[mi][ni][e], im = accI[mi][ni][e];
                pw[row * BN + (col ^ (row & 31))] = r * r + im * im;
            }
    __syncthreads();

    // ---- sparse mel projection + transposed store/atomic out[b][m][t]
    const int nbase = nb * BN;
    const int ti = tid & 127;
    {
        int g = gBase + ti;
        int b = g / NFRAMES, tt = g - b * NFRAMES;
        const int sw = ti & 31;
        const float* prow = pw + ti * BN;
        float* obase = out + (size_t)b * (NMELS * NFRAMES) + tt;
        for (int m = (tid >> 7); m < NMELS; m += 4) {
            int lo = klo[m], w = kw[m];
            int i0 = lo < nbase ? nbase : lo;
            int i1 = (lo + w < nbase + BN) ? (lo + w) : (nbase + BN);
            if (i1 <= i0) continue;
            float acc = 0.f;
            for (int j = i0; j < i1; ++j)
                acc += fbv[m * FBW + (j - lo)] * prow[(j - nbase) ^ sw];
            float* dst = obase + m * NFRAMES;
            bool full = (lo >= nbase) && (lo + w <= nbase + BN);
            if (full) *dst = acc;
            else      atomicAdd(dst, acc);
        }
    }
}

extern "C" void kernel_launch(void* const* d_in, const int* in_sizes, int n_in,
                              void* d_out, int out_size, void* d_ws, size_t ws_size,
                              hipStream_t stream) {
    const float* wav  = (const float*)d_in[0];
    const float* win  = (const float*)d_in[1];
    const float* dre  = (const float*)d_in[2];
    const float* dimg = (const float*)d_in[3];
    const float* mfb  = (const float*)d_in[4];
    float* out = (float*)d_out;

    uint8_t* ws = (uint8_t*)d_ws;
    uint16_t* BTf = (uint16_t*)ws;                       // 1 MB (fragment-major)
    uint16_t* wp  = (uint16_t*)(ws + (1u << 20));        // 16.9 MB
    size_t off = (1u << 20) + (size_t)NBATCH * XLEN * 2;
    int*   klo = (int*)(ws + off);
    int*   kw  = (int*)(ws + off + 640);
    float* fbv = (float*)(ws + off + 1280);

    hipLaunchKernelGGL(k_btf,  dim3(256),          dim3(256), 0, stream, dre, dimg, win, BTf);
    hipLaunchKernelGGL(k_pad,  dim3(XLEN/8/256 + 1, 256), dim3(256), 0, stream, wav, wp);
    hipLaunchKernelGGL(k_fb,   dim3(1),            dim3(192), 0, stream, mfb, klo, kw, fbv);
    hipLaunchKernelGGL(k_zero, dim3(256),          dim3(256), 0, stream, klo, kw, out);
    hipLaunchKernelGGL(k_main, dim3(TOTFR / BM, 2), dim3(512), 0, stream,
                       wp, BTf, klo, kw, fbv, out);
}